// Round 1
// baseline (417.354 us; speedup 1.0000x reference)
//
#include <hip/hip_runtime.h>
#include <cstddef>
#include <cstdint>

// MinGRU: g/v/d = x@W{g,v,d}^T + b; xs = sigmoid(g)*tanh(v); a = 0.001+0.998*sigmoid(d)
// h_t = a_t*h_{t-1} + xs_t (causal scan over S). Output h [B,S,D] f32.
// B=4, S=4096, D=1024.
// R7: (a) GEMM wave tile 64x48 -> 64x96 (BM=256, 4 waves 4Mx1N): LDS fragment
//     reads per MAC drop 0.071 -> 0.052 B/MAC (10 ds_read_b128 per 24 MFMA).
//     (b) k-slot XOR swizzle (slot ^= (row>>1)&3) on A/B tiles, applied on BOTH
//     sides (pre-swizzled global_load_lds source + swizzled read) -> kills the
//     8-way bank conflict on fragment ds_read_b128 (1.6e7 conflict cycles).
//     (c) scan2 (16 blocks, 256 serial iters, latency-bound) -> 3-level
//     segmented scan with 65536-thread parallel passes.
// Pipeline: cvt -> gemm_fused -> scan2a/b/c (segmented carry chain) -> scan3.

typedef _Float16 f16;
typedef f16 f16x8 __attribute__((ext_vector_type(8)));
typedef float f32x4 __attribute__((ext_vector_type(4)));

#define S_LEN 4096
#define D_DIM 1024
#define B_DIM 4
#define M_TOT (B_DIM * S_LEN)  // 16384
#define N_TOT (3 * D_DIM)      // 3072
#define K_TOT D_DIM            // 1024

#define CLEN 16
#define CPB (S_LEN / CLEN)   // 256 chunks per batch
#define NCHUNK (B_DIM * CPB) // 1024 total chunks

#define SEG 16               // chunks per scan segment
#define NSEG (CPB / SEG)     // 16 segments per batch

// ---------------- merged f32 -> f16 convert: x, then interleaved weights ----------------
__device__ __forceinline__ void cvt8(const float* s, f16* d) {
  f32x4 a = *(const f32x4*)s;
  f32x4 b = *(const f32x4*)(s + 4);
  f16x8 o;
  o[0] = (f16)a[0]; o[1] = (f16)a[1]; o[2] = (f16)a[2]; o[3] = (f16)a[3];
  o[4] = (f16)b[0]; o[5] = (f16)b[1]; o[6] = (f16)b[2]; o[7] = (f16)b[3];
  *(f16x8*)d = o;
}

__global__ void cvt_all_kernel(const float* __restrict__ x, const float* __restrict__ w0,
                               const float* __restrict__ w1, const float* __restrict__ w2,
                               f16* __restrict__ Ah, f16* __restrict__ Bh) {
  int i = (blockIdx.x * 256 + threadIdx.x) * 8;
  if (i < M_TOT * K_TOT) {
    cvt8(x + i, Ah + i);
  } else {
    int w = i - M_TOT * K_TOT;   // 0 .. 3*2^20
    int row = w >> 10;           // interleaved dst row 0..3071
    int col = w & 1023;
    int srow = row / 3;
    int mat = row - srow * 3;
    const float* s = (mat == 0) ? w0 : (mat == 1) ? w1 : w2;
    cvt8(s + srow * 1024 + col, Bh + w);
  }
}

// ---------------- fused GEMM + activation + chunk-local scan ----------------
#define BM 256
#define BN 96
#define BK 32
#define RAWP 100  // raw g/v/d tile pitch (halves), 128-row half-pass
#define XSP 32    // xs/a tile pitch (halves)

__device__ __forceinline__ void gl_lds16(const void* g, void* l) {
  __builtin_amdgcn_global_load_lds((const __attribute__((address_space(1))) void*)g,
                                   (__attribute__((address_space(3))) void*)l, 16, 0, 0);
}

__device__ __forceinline__ void act(float g, float v, float d, f16& xh, f16& ah) {
  float sg = 1.f / (1.f + __expf(-g));
  float tv = 1.f - 2.f / (__expf(2.f * v) + 1.f);
  float sd = 1.f / (1.f + __expf(-d));
  xh = (f16)(sg * tv);
  ah = (f16)(0.001f + 0.998f * sd);
}

// grid = (N_TOT/BN = 32, M_TOT/BM = 64), 256 threads = 4 waves, wave tile 64x96.
__global__ __launch_bounds__(256) void gemm_fused_kernel(
    const f16* __restrict__ A, const f16* __restrict__ Bt,
    const float* __restrict__ bg, const float* __restrict__ bv,
    const float* __restrict__ bd,
    f16* __restrict__ xsA, f16* __restrict__ aA,
    float* __restrict__ P, float* __restrict__ H) {
  // LDS (halves): staging As[0,8192) = 256x32, Bs[8192,11264) = 96x32;
  // epilogue overlay (per 128-row half-pass): Raw[0,12800) (128x100),
  // xsL[12800,16896), aL[16896,20992)
  __shared__ __attribute__((aligned(16))) f16 smem[20992];  // 41984 B
  f16* As = smem;
  f16* Bs = smem + 8192;
  const int tid = threadIdx.x;
  const int lane = tid & 63;
  const int wave = tid >> 6;
  const int m0 = blockIdx.y * BM;
  const int bn0 = blockIdx.x * BN;  // interleaved B row base (multiple of 3)

  // staging: each round = 256 threads x 16 B = 64 rows of 32 halves.
  // k-slot of each thread's 16B chunk is XOR-swizzled by (row>>1)&3 so the
  // (linear-dest) LDS tile holds the swizzled layout; rows 64r keep the same
  // swizzle ((64r+srow)>>1 & 3 == (srow>>1)&3), so one scol works for all rounds.
  const int srow = tid >> 2;
  const int scol = (((tid & 3) ^ ((tid >> 3) & 3)) * 8);
  const f16* aG = A + (size_t)(m0 + srow) * K_TOT + scol;
  const f16* bG0 = Bt + (size_t)(bn0 + srow) * K_TOT + scol;
  const f16* bG1 = Bt + (size_t)(bn0 + 64 + srow) * K_TOT + scol;  // tid<128 only
  f16* aL = As + tid * 8;
  f16* bL0 = Bs + tid * 8;
  f16* bL1 = Bs + 2048 + tid * 8;  // rows 64..95

  const int wm = wave * 64;       // wave owns rows wm..wm+63, all 96 cols
  const int lm = lane & 15;
  // read-side swizzle: global k-slot q=lane>>4 lives at position q ^ ((row>>1)&3);
  // (row>>1)&3 == (lm>>1)&3 for all row = 16*i + lm -> per-lane constant.
  const int kswz = (((lane >> 4) ^ ((lm >> 1) & 3)) << 3);

  f32x4 acc[4][6] = {};

  for (int k0 = 0; k0 < K_TOT; k0 += BK) {
#pragma unroll
    for (int r = 0; r < 4; ++r)
      gl_lds16(aG + (size_t)r * 64 * K_TOT + k0, aL + r * 2048);
    gl_lds16(bG0 + k0, bL0);
    if (tid < 128) gl_lds16(bG1 + k0, bL1);
    __syncthreads();  // drains vmcnt -> staging visible
    f16x8 af[4], bf[6];
#pragma unroll
    for (int i = 0; i < 4; ++i)
      af[i] = *(const f16x8*)&As[(wm + i * 16 + lm) * BK + kswz];
#pragma unroll
    for (int j = 0; j < 6; ++j)
      bf[j] = *(const f16x8*)&Bs[(j * 16 + lm) * BK + kswz];
#pragma unroll
    for (int i = 0; i < 4; ++i)
#pragma unroll
      for (int j = 0; j < 6; ++j)
        acc[i][j] = __builtin_amdgcn_mfma_f32_16x16x32_f16(af[i], bf[j], acc[i][j], 0, 0, 0);
    __syncthreads();  // protect LDS before next stage / epilogue overlay
  }

  // ---- epilogue: two 128-row half-passes (waves 0,1 then waves 2,3) ----
  f16* Raw = smem;
  f16* xsL = smem + 12800;
  f16* aLs = smem + 16896;
  const int d = tid & 31;
  const int cc = tid >> 5;  // 0..7 (8 chunks of 16 rows per half-pass)
  const int gd = (blockIdx.x << 5) + d;
  const float Bg = bg[gd], Bv = bv[gd], Bd_ = bd[gd];

#pragma unroll
  for (int half = 0; half < 2; ++half) {
    // 1) raw g/v/d -> LDS transpose tile (f16, same rounding as before)
    if ((wave >> 1) == half) {
      const int r0 = (wave & 1) * 64 + ((lane >> 4) << 2);  // local row in half
      const int c0 = lane & 15;
#pragma unroll
      for (int i = 0; i < 4; ++i)
#pragma unroll
        for (int j = 0; j < 6; ++j)
#pragma unroll
          for (int r = 0; r < 4; ++r)
            Raw[(r0 + i * 16 + r) * RAWP + c0 + j * 16] = (f16)acc[i][j][r];
    }
    __syncthreads();

    // 2) activation + chunk-local scan; thread = (chunk cc, channel d)
    {
      float p = 1.f, h = 0.f;
#pragma unroll
      for (int i = 0; i < CLEN; ++i) {
        const int r = cc * CLEN + i;
        const f16* t3 = &Raw[r * RAWP + 3 * d];
        f16 xh, ah;
        act((float)t3[0] + Bg, (float)t3[1] + Bv, (float)t3[2] + Bd_, xh, ah);
        xsL[r * XSP + d] = xh;
        aLs[r * XSP + d] = ah;
        // use ROUNDED values so scan3 recomposition is exactly consistent
        float xf = (float)xh, af_ = (float)ah;
        h = af_ * h + xf;
        p *= af_;
      }
      const int gs = (m0 >> 4) + half * 8 + cc;  // global chunk index = m/16
      P[(size_t)gs * D_DIM + gd] = p;
      H[(size_t)gs * D_DIM + gd] = h;
    }
    __syncthreads();

    // 3) coalesced xs/a global stores (2 rounds x 64 rows)
#pragma unroll
    for (int rr = 0; rr < 2; ++rr) {
      const int row = rr * 64 + (tid >> 2);
      const int col = (tid & 3) * 8;
      const size_t gi = (size_t)(m0 + half * 128 + row) * D_DIM + (blockIdx.x << 5) + col;
      *(f16x8*)(xsA + gi) = *(const f16x8*)&xsL[row * XSP + col];
      *(f16x8*)(aA + gi) = *(const f16x8*)&aLs[row * XSP + col];
    }
    __syncthreads();  // half=1 overwrites Raw/xsL/aL
  }
}

// ---------------- scan pass 2: segmented 3-level carry chain ----------------
// 2a: per-segment (16 chunks) aggregate: SP = prod(P), SH = scan-h within seg.
__global__ void scan2a_kernel(const float* __restrict__ P, const float* __restrict__ H,
                              float* __restrict__ SP, float* __restrict__ SH) {
  const int u = blockIdx.x * 256 + threadIdx.x;  // 0..65535
  const int d = u & 1023;
  const int s = (u >> 10) & (NSEG - 1);
  const int b = u >> 14;
  const int gs0 = b * CPB + s * SEG;
  float p = 1.f, h = 0.f;
#pragma unroll 4
  for (int c = 0; c < SEG; ++c) {
    const size_t off = (size_t)(gs0 + c) * D_DIM + d;
    const float pp = P[off], hh = H[off];
    h = pp * h + hh;
    p *= pp;
  }
  const size_t so = (size_t)(b * NSEG + s) * D_DIM + d;
  SP[so] = p;
  SH[so] = h;
}

// 2b: chain carries across the 16 segments per batch (short serial loop).
__global__ void scan2b_kernel(const float* __restrict__ SP, const float* __restrict__ SH,
                              float* __restrict__ segC) {
  const int idx = blockIdx.x * 256 + threadIdx.x;  // 0..4095 = b*1024+d
  const int b = idx >> 10;
  const int d = idx & 1023;
  float h = 0.f;
  for (int s = 0; s < NSEG; ++s) {
    const size_t off = (size_t)(b * NSEG + s) * D_DIM + d;
    segC[off] = h;
    h = SP[off] * h + SH[off];
  }
}

// 2c: expand segment carries to per-chunk carries (parallel across segments).
__global__ void scan2c_kernel(const float* __restrict__ P, const float* __restrict__ H,
                              const float* __restrict__ segC, float* __restrict__ carry) {
  const int u = blockIdx.x * 256 + threadIdx.x;  // 0..65535
  const int d = u & 1023;
  const int s = (u >> 10) & (NSEG - 1);
  const int b = u >> 14;
  float h = segC[(size_t)(b * NSEG + s) * D_DIM + d];
  const int gs0 = b * CPB + s * SEG;
#pragma unroll 4
  for (int c = 0; c < SEG; ++c) {
    const size_t off = (size_t)(gs0 + c) * D_DIM + d;
    carry[off] = h;
    h = P[off] * h + H[off];
  }
}

// ---------------- scan pass 3: rescan with carry, write output ----------------
__global__ void scan3_kernel(const f16* __restrict__ xsA, const f16* __restrict__ aA,
                             const float* __restrict__ carry, float* __restrict__ out) {
  const int u = blockIdx.x * 256 + threadIdx.x;
  const int cg = u & 127;
  const int b = (u >> 7) & 3;
  const int ck = u >> 9;  // 0..255
  const int ch = cg * 8;
  const int base = (b * CPB + ck) * D_DIM + ch;
  float h[8];
  *(f32x4*)h = *(const f32x4*)(carry + base);
  *(f32x4*)(h + 4) = *(const f32x4*)(carry + base + 4);
  const int t0 = ck * CLEN;
#pragma unroll 2
  for (int t = t0; t < t0 + CLEN; ++t) {
    const size_t m = (size_t)b * S_LEN + t;
    f16x8 xs8 = *(const f16x8*)(xsA + m * D_DIM + ch);
    f16x8 a8 = *(const f16x8*)(aA + m * D_DIM + ch);
#pragma unroll
    for (int j = 0; j < 8; ++j) h[j] = (float)a8[j] * h[j] + (float)xs8[j];
    float* op = out + m * D_DIM + ch;
    *(f32x4*)op = *(f32x4*)h;
    *(f32x4*)(op + 4) = *(f32x4*)(h + 4);
  }
}

extern "C" void kernel_launch(void* const* d_in, const int* in_sizes, int n_in,
                              void* d_out, int out_size, void* d_ws, size_t ws_size,
                              hipStream_t stream) {
  const float* x = (const float*)d_in[0];
  const float* Wg = (const float*)d_in[1];
  const float* bg = (const float*)d_in[2];
  const float* Wv = (const float*)d_in[3];
  const float* bv = (const float*)d_in[4];
  const float* Wd = (const float*)d_in[5];
  const float* bd = (const float*)d_in[6];
  float* out = (float*)d_out;

  // workspace layout (~114 MB). SP/SH/segC overlay the Ah region: Ah is dead
  // once gemm_fused completes, and scan2a runs strictly after it on the stream.
  char* ws = (char*)d_ws;
  f16* Ah = (f16*)(ws);                     // 33,554,432 B
  f16* Bh = (f16*)(ws + 33554432);          // 6,291,456 B (interleaved weights)
  f16* xsA = (f16*)(ws + 39845888);         // 33,554,432 B
  f16* aA = (f16*)(ws + 73400320);          // 33,554,432 B
  float* P = (float*)(ws + 106954752);      // NCHUNK*1024*4 = 4,194,304 B
  float* H = (float*)(ws + 111149056);      // 4,194,304 B
  float* carry = (float*)(ws + 115343360);  // 4,194,304 B
  float* SP = (float*)(ws);                 // 262,144 B (overlays dead Ah)
  float* SH = (float*)(ws + 262144);        // 262,144 B
  float* segC = (float*)(ws + 524288);      // 262,144 B

  cvt_all_kernel<<<9728, 256, 0, stream>>>(x, Wg, Wv, Wd, Ah, Bh);
  gemm_fused_kernel<<<dim3(N_TOT / BN, M_TOT / BM), 256, 0, stream>>>(
      Ah, Bh, bg, bv, bd, xsA, aA, P, H);
  scan2a_kernel<<<256, 256, 0, stream>>>(P, H, SP, SH);
  scan2b_kernel<<<16, 256, 0, stream>>>(SP, SH, segC);
  scan2c_kernel<<<256, 256, 0, stream>>>(P, H, segC, carry);
  scan3_kernel<<<512, 256, 0, stream>>>(xsA, aA, carry, out);
}

// Round 3
// 333.379 us; speedup vs baseline: 1.2519x; 1.2519x over previous
//
#include <hip/hip_runtime.h>
#include <cstddef>
#include <cstdint>

// MinGRU: g/v/d = x@W{g,v,d}^T + b; xs = sigmoid(g)*tanh(v); a = 0.001+0.998*sigmoid(d)
// h_t = a_t*h_{t-1} + xs_t (causal scan over S). Output h [B,S,D] f32.
// B=4, S=4096, D=1024.
// R8 (resubmit; prior run died on container acquisition, not kernel):
//     revert R7's BM=256 (VGPR 132+96acc -> occupancy cliff, MfmaUtil 15%).
//     Keep R7's verified k-slot XOR swizzle (bank conflicts 1.6e7 -> 1.6e6).
//     Shape back to BM=128 / wave 64x48 / acc[4][3] (~116 total regs = 4 w/SIMD),
//     and halve LDS 41984 -> 20992 B by running the epilogue as two 64-row
//     half-passes -> 4 blocks/CU (was 3, LDS-bound). scan2b folded into scan2c.
// Pipeline: cvt -> gemm_fused -> scan2a -> scan2bc -> scan3.

typedef _Float16 f16;
typedef f16 f16x8 __attribute__((ext_vector_type(8)));
typedef float f32x4 __attribute__((ext_vector_type(4)));

#define S_LEN 4096
#define D_DIM 1024
#define B_DIM 4
#define M_TOT (B_DIM * S_LEN)  // 16384
#define N_TOT (3 * D_DIM)      // 3072
#define K_TOT D_DIM            // 1024

#define CLEN 16
#define CPB (S_LEN / CLEN)   // 256 chunks per batch
#define NCHUNK (B_DIM * CPB) // 1024 total chunks

#define SEG 16               // chunks per scan segment
#define NSEG (CPB / SEG)     // 16 segments per batch

// ---------------- merged f32 -> f16 convert: x, then interleaved weights ----------------
__device__ __forceinline__ void cvt8(const float* s, f16* d) {
  f32x4 a = *(const f32x4*)s;
  f32x4 b = *(const f32x4*)(s + 4);
  f16x8 o;
  o[0] = (f16)a[0]; o[1] = (f16)a[1]; o[2] = (f16)a[2]; o[3] = (f16)a[3];
  o[4] = (f16)b[0]; o[5] = (f16)b[1]; o[6] = (f16)b[2]; o[7] = (f16)b[3];
  *(f16x8*)d = o;
}

__global__ void cvt_all_kernel(const float* __restrict__ x, const float* __restrict__ w0,
                               const float* __restrict__ w1, const float* __restrict__ w2,
                               f16* __restrict__ Ah, f16* __restrict__ Bh) {
  int i = (blockIdx.x * 256 + threadIdx.x) * 8;
  if (i < M_TOT * K_TOT) {
    cvt8(x + i, Ah + i);
  } else {
    int w = i - M_TOT * K_TOT;   // 0 .. 3*2^20
    int row = w >> 10;           // interleaved dst row 0..3071
    int col = w & 1023;
    int srow = row / 3;
    int mat = row - srow * 3;
    const float* s = (mat == 0) ? w0 : (mat == 1) ? w1 : w2;
    cvt8(s + srow * 1024 + col, Bh + w);
  }
}

// ---------------- fused GEMM + activation + chunk-local scan ----------------
#define BM 128
#define BN 96
#define BK 32
#define RAWP 100  // raw g/v/d tile pitch (halves), 64-row half-pass
#define XSP 32    // xs/a tile pitch (halves)

__device__ __forceinline__ void gl_lds16(const void* g, void* l) {
  __builtin_amdgcn_global_load_lds((const __attribute__((address_space(1))) void*)g,
                                   (__attribute__((address_space(3))) void*)l, 16, 0, 0);
}

__device__ __forceinline__ void act(float g, float v, float d, f16& xh, f16& ah) {
  float sg = 1.f / (1.f + __expf(-g));
  float tv = 1.f - 2.f / (__expf(2.f * v) + 1.f);
  float sd = 1.f / (1.f + __expf(-d));
  xh = (f16)(sg * tv);
  ah = (f16)(0.001f + 0.998f * sd);
}

// grid = (N_TOT/BN = 32, M_TOT/BM = 128), 256 threads = 4 waves, wave tile 64x48.
__global__ __launch_bounds__(256) void gemm_fused_kernel(
    const f16* __restrict__ A, const f16* __restrict__ Bt,
    const float* __restrict__ bg, const float* __restrict__ bv,
    const float* __restrict__ bd,
    f16* __restrict__ xsA, f16* __restrict__ aA,
    float* __restrict__ P, float* __restrict__ H) {
  // LDS (halves): staging As[0,4096) = 128x32, Bs[4096,7168) = 96x32;
  // epilogue overlay per 64-row half-pass: Raw[0,6400) (64x100),
  // xsL[6400,8448), aL[8448,10496).  Total 20992 B -> 4 blocks/CU.
  __shared__ __attribute__((aligned(16))) f16 smem[10496];
  f16* As = smem;
  f16* Bs = smem + 4096;
  const int tid = threadIdx.x;
  const int lane = tid & 63;
  const int wave = tid >> 6;
  const int m0 = blockIdx.y * BM;
  const int bn0 = blockIdx.x * BN;  // interleaved B row base (multiple of 3)

  // staging: each round = 256 threads x 16 B = 64 rows of 32 halves.
  // k-slot of each thread's 16B chunk is XOR-swizzled by (row>>1)&3; the LDS
  // dest stays linear, the global SOURCE k-slot is pre-swizzled (rule #21).
  // Rows at +64 offset keep the same swizzle ((row+64)>>1 & 3 == (row>>1)&3).
  const int srow = tid >> 2;
  const int scol = ((tid & 3) ^ ((tid >> 3) & 3)) * 8;
  const f16* aG0 = A + (size_t)(m0 + srow) * K_TOT + scol;
  const f16* aG1 = A + (size_t)(m0 + srow + 64) * K_TOT + scol;
  const f16* bG0 = Bt + (size_t)(bn0 + srow) * K_TOT + scol;
  const f16* bG1 = Bt + (size_t)(bn0 + 64 + srow) * K_TOT + scol;  // tid<128 only
  f16* aL0 = As + tid * 8;
  f16* aL1 = As + 2048 + tid * 8;
  f16* bL0 = Bs + tid * 8;
  f16* bL1 = Bs + 2048 + tid * 8;  // rows 64..95

  const int wm = (wave >> 1) * 64;  // 0 / 64
  const int wn = (wave & 1) * 48;   // 0 / 48
  const int lm = lane & 15;
  // read-side swizzle: logical k-slot q=lane>>4 sits at q ^ ((row>>1)&3);
  // (row>>1)&3 == (lm>>1)&3 for row = 16*i + lm -> per-lane constant.
  const int kswz = (((lane >> 4) ^ ((lm >> 1) & 3)) << 3);

  f32x4 acc[4][3] = {};

  for (int k0 = 0; k0 < K_TOT; k0 += BK) {
    gl_lds16(aG0 + k0, aL0);
    gl_lds16(aG1 + k0, aL1);
    gl_lds16(bG0 + k0, bL0);
    if (tid < 128) gl_lds16(bG1 + k0, bL1);
    __syncthreads();  // drains vmcnt -> staging visible
    f16x8 af[4], bf[3];
#pragma unroll
    for (int i = 0; i < 4; ++i)
      af[i] = *(const f16x8*)&As[(wm + i * 16 + lm) * BK + kswz];
#pragma unroll
    for (int j = 0; j < 3; ++j)
      bf[j] = *(const f16x8*)&Bs[(wn + j * 16 + lm) * BK + kswz];
#pragma unroll
    for (int i = 0; i < 4; ++i)
#pragma unroll
      for (int j = 0; j < 3; ++j)
        acc[i][j] = __builtin_amdgcn_mfma_f32_16x16x32_f16(af[i], bf[j], acc[i][j], 0, 0, 0);
    __syncthreads();  // protect LDS before next stage / epilogue overlay
  }

  // ---- epilogue: two 64-row half-passes (waves 0,1 dump, then waves 2,3) ----
  f16* Raw = smem;
  f16* xsL = smem + 6400;
  f16* aLs = smem + 8448;
  const int d = tid & 31;
  const int cc = (tid >> 5) & 3;  // chunk within half-pass (tid<128 active)
  const int gd = (blockIdx.x << 5) + d;
  const float Bg = bg[gd], Bv = bv[gd], Bd_ = bd[gd];

#pragma unroll
  for (int half = 0; half < 2; ++half) {
    // 1) raw g/v/d -> LDS transpose tile (f16, same rounding as before)
    if ((wave >> 1) == half) {
      const int r0 = (lane >> 4) << 2;               // local row in half-pass
      const int c0 = (wave & 1) * 48 + (lane & 15);  // channel-triple column
#pragma unroll
      for (int i = 0; i < 4; ++i)
#pragma unroll
        for (int j = 0; j < 3; ++j)
#pragma unroll
          for (int r = 0; r < 4; ++r)
            Raw[(r0 + i * 16 + r) * RAWP + c0 + j * 16] = (f16)acc[i][j][r];
    }
    __syncthreads();

    // 2) activation + chunk-local scan; thread = (chunk cc, channel d)
    if (tid < 128) {
      float p = 1.f, h = 0.f;
#pragma unroll
      for (int i = 0; i < CLEN; ++i) {
        const int r = cc * CLEN + i;
        const f16* t3 = &Raw[r * RAWP + 3 * d];
        f16 xh, ah;
        act((float)t3[0] + Bg, (float)t3[1] + Bv, (float)t3[2] + Bd_, xh, ah);
        xsL[r * XSP + d] = xh;
        aLs[r * XSP + d] = ah;
        // use ROUNDED values so scan3 recomposition is exactly consistent
        float xf = (float)xh, af_ = (float)ah;
        h = af_ * h + xf;
        p *= af_;
      }
      const int gs = (m0 >> 4) + half * 4 + cc;  // global chunk index = m/16
      P[(size_t)gs * D_DIM + gd] = p;
      H[(size_t)gs * D_DIM + gd] = h;
    }
    __syncthreads();

    // 3) coalesced xs/a global stores (64 rows x 32 cols = 1 round)
    {
      const int row = tid >> 2;
      const int col = (tid & 3) * 8;
      const size_t gi = (size_t)(m0 + half * 64 + row) * D_DIM + (blockIdx.x << 5) + col;
      *(f16x8*)(xsA + gi) = *(const f16x8*)&xsL[row * XSP + col];
      *(f16x8*)(aA + gi) = *(const f16x8*)&aLs[row * XSP + col];
    }
    __syncthreads();  // half=1 overwrites Raw/xsL/aLs
  }
}

// ---------------- scan pass 2: segmented carry chain ----------------
// 2a: per-segment (16 chunks) aggregate: SP = prod(P), SH = scan-h within seg.
__global__ void scan2a_kernel(const float* __restrict__ P, const float* __restrict__ H,
                              float* __restrict__ SP, float* __restrict__ SH) {
  const int u = blockIdx.x * 256 + threadIdx.x;  // 0..65535
  const int d = u & 1023;
  const int s = (u >> 10) & (NSEG - 1);
  const int b = u >> 14;
  const int gs0 = b * CPB + s * SEG;
  float p = 1.f, h = 0.f;
#pragma unroll 4
  for (int c = 0; c < SEG; ++c) {
    const size_t off = (size_t)(gs0 + c) * D_DIM + d;
    const float pp = P[off], hh = H[off];
    h = pp * h + hh;
    p *= pp;
  }
  const size_t so = (size_t)(b * NSEG + s) * D_DIM + d;
  SP[so] = p;
  SH[so] = h;
}

// 2bc: chain segment aggregates (redundantly per block; s uniform within block)
//      then expand to per-chunk carries.
__global__ void scan2bc_kernel(const float* __restrict__ P, const float* __restrict__ H,
                               const float* __restrict__ SP, const float* __restrict__ SH,
                               float* __restrict__ carry) {
  const int u = blockIdx.x * 256 + threadIdx.x;  // 0..65535
  const int d = u & 1023;
  const int s = (u >> 10) & (NSEG - 1);  // uniform within a 256-thread block
  const int b = u >> 14;
  float h = 0.f;
  for (int s2 = 0; s2 < s; ++s2) {
    const size_t off = (size_t)(b * NSEG + s2) * D_DIM + d;
    h = SP[off] * h + SH[off];
  }
  const int gs0 = b * CPB + s * SEG;
#pragma unroll 4
  for (int c = 0; c < SEG; ++c) {
    const size_t off = (size_t)(gs0 + c) * D_DIM + d;
    carry[off] = h;
    h = P[off] * h + H[off];
  }
}

// ---------------- scan pass 3: rescan with carry, write output ----------------
__global__ void scan3_kernel(const f16* __restrict__ xsA, const f16* __restrict__ aA,
                             const float* __restrict__ carry, float* __restrict__ out) {
  const int u = blockIdx.x * 256 + threadIdx.x;
  const int cg = u & 127;
  const int b = (u >> 7) & 3;
  const int ck = u >> 9;  // 0..255
  const int ch = cg * 8;
  const int base = (b * CPB + ck) * D_DIM + ch;
  float h[8];
  *(f32x4*)h = *(const f32x4*)(carry + base);
  *(f32x4*)(h + 4) = *(const f32x4*)(carry + base + 4);
  const int t0 = ck * CLEN;
#pragma unroll 2
  for (int t = t0; t < t0 + CLEN; ++t) {
    const size_t m = (size_t)b * S_LEN + t;
    f16x8 xs8 = *(const f16x8*)(xsA + m * D_DIM + ch);
    f16x8 a8 = *(const f16x8*)(aA + m * D_DIM + ch);
#pragma unroll
    for (int j = 0; j < 8; ++j) h[j] = (float)a8[j] * h[j] + (float)xs8[j];
    float* op = out + m * D_DIM + ch;
    *(f32x4*)op = *(f32x4*)h;
    *(f32x4*)(op + 4) = *(f32x4*)(h + 4);
  }
}

extern "C" void kernel_launch(void* const* d_in, const int* in_sizes, int n_in,
                              void* d_out, int out_size, void* d_ws, size_t ws_size,
                              hipStream_t stream) {
  const float* x = (const float*)d_in[0];
  const float* Wg = (const float*)d_in[1];
  const float* bg = (const float*)d_in[2];
  const float* Wv = (const float*)d_in[3];
  const float* bv = (const float*)d_in[4];
  const float* Wd = (const float*)d_in[5];
  const float* bd = (const float*)d_in[6];
  float* out = (float*)d_out;

  // workspace layout (~114 MB). SP/SH overlay the Ah region: Ah is dead once
  // gemm_fused completes, and scan2a runs strictly after it on the stream.
  char* ws = (char*)d_ws;
  f16* Ah = (f16*)(ws);                     // 33,554,432 B
  f16* Bh = (f16*)(ws + 33554432);          // 6,291,456 B (interleaved weights)
  f16* xsA = (f16*)(ws + 39845888);         // 33,554,432 B
  f16* aA = (f16*)(ws + 73400320);          // 33,554,432 B
  float* P = (float*)(ws + 106954752);      // NCHUNK*1024*4 = 4,194,304 B
  float* H = (float*)(ws + 111149056);      // 4,194,304 B
  float* carry = (float*)(ws + 115343360);  // 4,194,304 B
  float* SP = (float*)(ws);                 // 262,144 B (overlays dead Ah)
  float* SH = (float*)(ws + 262144);        // 262,144 B

  cvt_all_kernel<<<9728, 256, 0, stream>>>(x, Wg, Wv, Wd, Ah, Bh);
  gemm_fused_kernel<<<dim3(N_TOT / BN, M_TOT / BM), 256, 0, stream>>>(
      Ah, Bh, bg, bv, bd, xsA, aA, P, H);
  scan2a_kernel<<<256, 256, 0, stream>>>(P, H, SP, SH);
  scan2bc_kernel<<<256, 256, 0, stream>>>(P, H, SP, SH, carry);
  scan3_kernel<<<512, 256, 0, stream>>>(xsA, aA, carry, out);
}

// Round 4
// 285.701 us; speedup vs baseline: 1.4608x; 1.1669x over previous
//
#include <hip/hip_runtime.h>
#include <cstddef>
#include <cstdint>

// MinGRU: g/v/d = x@W{g,v,d}^T + b; xs = sigmoid(g)*tanh(v); a = 0.001+0.998*sigmoid(d)
// h_t = a_t*h_{t-1} + xs_t (causal scan over S). Output h [B,S,D] f32.
// B=4, S=4096, D=1024.
// R9: GEMM was staging-BW-bound (intensity BM*BN/(BM+BN)=54.9 FLOP/B -> 23%
//     MfmaUtil matched L2-delivery arithmetic). Fix = bigger tile + prefetch:
//     256x192 tile, BK=64, 512 threads (wave tile 64x96, acc[4][6]),
//     double-buffered LDS (112KB) with STAGE-next-before-compute and ONE
//     barrier per K-tile (T3 minimum-2-phase recipe). Intensity 109.7 FLOP/B;
//     per-K-tile MFMA (~1550cy) > HBM latency (~900cy) -> drain hidden.
//     K-slot XOR swizzle (slot ^= row&7, both sides) now load-bearing at
//     pitch 128B. Bijective XCD swizzle for A-panel L2 locality.
// Pipeline: cvt -> gemm_fused -> scan2a -> scan2bc -> scan3.

typedef _Float16 f16;
typedef f16 f16x8 __attribute__((ext_vector_type(8)));
typedef float f32x4 __attribute__((ext_vector_type(4)));

#define S_LEN 4096
#define D_DIM 1024
#define B_DIM 4
#define M_TOT (B_DIM * S_LEN)  // 16384
#define N_TOT (3 * D_DIM)      // 3072
#define K_TOT D_DIM            // 1024

#define CLEN 16
#define CPB (S_LEN / CLEN)   // 256 chunks per batch
#define NCHUNK (B_DIM * CPB) // 1024 total chunks

#define SEG 16               // chunks per scan segment
#define NSEG (CPB / SEG)     // 16 segments per batch

// ---------------- merged f32 -> f16 convert: x, then interleaved weights ----------------
__device__ __forceinline__ void cvt8(const float* s, f16* d) {
  f32x4 a = *(const f32x4*)s;
  f32x4 b = *(const f32x4*)(s + 4);
  f16x8 o;
  o[0] = (f16)a[0]; o[1] = (f16)a[1]; o[2] = (f16)a[2]; o[3] = (f16)a[3];
  o[4] = (f16)b[0]; o[5] = (f16)b[1]; o[6] = (f16)b[2]; o[7] = (f16)b[3];
  *(f16x8*)d = o;
}

__global__ void cvt_all_kernel(const float* __restrict__ x, const float* __restrict__ w0,
                               const float* __restrict__ w1, const float* __restrict__ w2,
                               f16* __restrict__ Ah, f16* __restrict__ Bh) {
  int i = (blockIdx.x * 256 + threadIdx.x) * 8;
  if (i < M_TOT * K_TOT) {
    cvt8(x + i, Ah + i);
  } else {
    int w = i - M_TOT * K_TOT;   // 0 .. 3*2^20
    int row = w >> 10;           // interleaved dst row 0..3071
    int col = w & 1023;
    int srow = row / 3;
    int mat = row - srow * 3;
    const float* s = (mat == 0) ? w0 : (mat == 1) ? w1 : w2;
    cvt8(s + srow * 1024 + col, Bh + w);
  }
}

// ---------------- fused GEMM + activation + chunk-local scan ----------------
#define BM 256
#define BN 192
#define BK 64
#define RAWP 200  // raw g/v/d tile pitch (halves), 128-row half-pass
#define XSP 72    // xs/a tile pitch (halves), padded vs bank conflicts

// LDS layout (halves):
//   As buf0 [0,16384)  buf1 [16384,32768)     (256 rows x 64)
//   Bs buf0 [32768,45056) buf1 [45056,57344)  (192 rows x 64)
// epilogue overlay (after final barrier): Raw [0,25600) = 128x200,
//   xsL [25600,34816) = 128x72, aL [34816,44032) = 128x72.
#define AS_OFF 0
#define BS_OFF 32768
#define ABUF 16384
#define BBUF 12288
#define SMEM_H 57344  // 114688 B

__device__ __forceinline__ void gl_lds16(const void* g, void* l) {
  __builtin_amdgcn_global_load_lds((const __attribute__((address_space(1))) void*)g,
                                   (__attribute__((address_space(3))) void*)l, 16, 0, 0);
}

__device__ __forceinline__ void act(float g, float v, float d, f16& xh, f16& ah) {
  float sg = 1.f / (1.f + __expf(-g));
  float tv = 1.f - 2.f / (__expf(2.f * v) + 1.f);
  float sd = 1.f / (1.f + __expf(-d));
  xh = (f16)(sg * tv);
  ah = (f16)(0.001f + 0.998f * sd);
}

// grid = 1024 blocks (XCD-swizzled to 16 N x 64 M), 512 threads = 8 waves.
__global__ __launch_bounds__(512, 2) void gemm_fused_kernel(
    const f16* __restrict__ A, const f16* __restrict__ Bt,
    const float* __restrict__ bg, const float* __restrict__ bv,
    const float* __restrict__ bd,
    f16* __restrict__ xsA, f16* __restrict__ aA,
    float* __restrict__ P, float* __restrict__ H) {
  __shared__ __attribute__((aligned(16))) f16 smem[SMEM_H];
  const int tid = threadIdx.x;
  const int lane = tid & 63;
  const int wave = tid >> 6;

  // bijective XCD swizzle (nwg=1024 % 8 == 0): XCD c owns 128 consecutive
  // orig ids = 8 M-panels x 16 N-blocks, N-major -> A panel stays L2-hot.
  const int wg = blockIdx.x;
  const int orig = (wg & 7) * 128 + (wg >> 3);
  const int bx = orig & 15;   // N block 0..15
  const int by = orig >> 4;   // M block 0..63
  const int m0 = by * BM;
  const int bn0 = bx * BN;    // interleaved B row base (multiple of 3)

  // ---- staging addressing: round = 512 threads x 16B = 64 rows x 8 slots ----
  // LDS dest is linear (gl_lds requirement); the global SOURCE k-slot is
  // pre-swizzled: LDS[row][s] holds global slot s ^ (row&7)  (involution).
  const int srow = tid >> 3;                        // 0..63
  const int sslot = (tid & 7) ^ (srow & 7);         // swizzled source slot
  const f16* aSrc = A + (size_t)(m0 + srow) * K_TOT + sslot * 8;
  const f16* bSrc = Bt + (size_t)(bn0 + srow) * K_TOT + sslot * 8;
  f16* aDst0 = smem + AS_OFF + tid * 8;             // + buf*ABUF + r*4096
  f16* bDst0 = smem + BS_OFF + tid * 8;             // + buf*BBUF + r*4096

  // ---- fragment addressing ----
  const int wm = (wave >> 1) * 64;  // 0/64/128/192
  const int wn = (wave & 1) * 96;   // 0/96
  const int lm = lane & 15;
  const int q = lane >> 4;
  // read-side swizzle: logical slot (kk*4+q) lives at (kk*4+q)^(row&7);
  // row&7 == lm&7 for all fragment rows (wm, i*16, j*16 are 0 mod 8).
  const int sw0 = ((0 * 4 + q) ^ (lm & 7)) * 8;
  const int sw1 = ((1 * 4 + q) ^ (lm & 7)) * 8;

  f32x4 acc[4][6] = {};

  // ---- prologue: stage K-tile 0 into buf 0, drain, barrier ----
#pragma unroll
  for (int r = 0; r < 4; ++r)
    gl_lds16(aSrc + (size_t)r * 64 * K_TOT, aDst0 + r * 4096);
#pragma unroll
  for (int r = 0; r < 3; ++r)
    gl_lds16(bSrc + (size_t)r * 64 * K_TOT, bDst0 + r * 4096);
  __syncthreads();

  // ---- main loop: 16 K-tiles; STAGE next (other buf) BEFORE compute, one
  //      barrier per tile (syncthreads drains vmcnt+lgkm -> next tile ready).
  for (int t = 0; t < 16; ++t) {
    const int cur = t & 1;
    if (t < 15) {
      const int nxt = cur ^ 1;
      const size_t k0 = (size_t)(t + 1) * BK;
#pragma unroll
      for (int r = 0; r < 4; ++r)
        gl_lds16(aSrc + (size_t)r * 64 * K_TOT + k0, aDst0 + nxt * ABUF + r * 4096);
#pragma unroll
      for (int r = 0; r < 3; ++r)
        gl_lds16(bSrc + (size_t)r * 64 * K_TOT + k0, bDst0 + nxt * BBUF + r * 4096);
    }
    const f16* Acur = smem + AS_OFF + cur * ABUF;
    const f16* Bcur = smem + BS_OFF + cur * BBUF;
#pragma unroll
    for (int kk = 0; kk < 2; ++kk) {
      const int sw = kk ? sw1 : sw0;
      f16x8 af[4], bf[6];
#pragma unroll
      for (int i = 0; i < 4; ++i)
        af[i] = *(const f16x8*)&Acur[(wm + i * 16 + lm) * BK + sw];
#pragma unroll
      for (int j = 0; j < 6; ++j)
        bf[j] = *(const f16x8*)&Bcur[(wn + j * 16 + lm) * BK + sw];
#pragma unroll
      for (int i = 0; i < 4; ++i)
#pragma unroll
        for (int j = 0; j < 6; ++j)
          acc[i][j] = __builtin_amdgcn_mfma_f32_16x16x32_f16(af[i], bf[j], acc[i][j], 0, 0, 0);
    }
    __syncthreads();
  }

  // ---- epilogue: two 128-row half-passes through LDS overlay ----
  f16* Raw = smem;
  f16* xsL = smem + 25600;
  f16* aLs = smem + 34816;
  const int d = tid & 63;        // channel within block (64 channels)
  const int cc = tid >> 6;       // chunk 0..7 within half-pass
  const int gd = (bx << 6) + d;  // global channel
  const float Bg = bg[gd], Bv = bv[gd], Bd_ = bd[gd];

#pragma unroll
  for (int half = 0; half < 2; ++half) {
    // 1) raw g/v/d -> LDS tile (f16, rounding contract shared with scan3)
    if ((wave >> 2) == half) {
      const int r0 = ((wave >> 1) & 1) * 64 + ((lane >> 4) << 2);  // row in half
      const int c0 = wn + (lane & 15);
#pragma unroll
      for (int i = 0; i < 4; ++i)
#pragma unroll
        for (int j = 0; j < 6; ++j)
#pragma unroll
          for (int r = 0; r < 4; ++r)
            Raw[(r0 + i * 16 + r) * RAWP + c0 + j * 16] = (f16)acc[i][j][r];
    }
    __syncthreads();

    // 2) activation + chunk-local scan; thread = (chunk cc, channel d)
    {
      float p = 1.f, h = 0.f;
#pragma unroll
      for (int i = 0; i < CLEN; ++i) {
        const int r = cc * CLEN + i;
        const f16* t3 = &Raw[r * RAWP + 3 * d];
        f16 xh, ah;
        act((float)t3[0] + Bg, (float)t3[1] + Bv, (float)t3[2] + Bd_, xh, ah);
        xsL[r * XSP + d] = xh;
        aLs[r * XSP + d] = ah;
        // use ROUNDED values so scan3 recomposition is exactly consistent
        float xf = (float)xh, af_ = (float)ah;
        h = af_ * h + xf;
        p *= af_;
      }
      const int gs = (m0 >> 4) + half * 8 + cc;  // global chunk index = m/16
      P[(size_t)gs * D_DIM + gd] = p;
      H[(size_t)gs * D_DIM + gd] = h;
    }
    __syncthreads();

    // 3) coalesced xs/a global stores (2 rounds x 64 rows x 64 cols)
#pragma unroll
    for (int rr = 0; rr < 2; ++rr) {
      const int row = rr * 64 + (tid >> 3);
      const int col = (tid & 7) * 8;
      const size_t gi = (size_t)(m0 + half * 128 + row) * D_DIM + (bx << 6) + col;
      *(f16x8*)(xsA + gi) = *(const f16x8*)&xsL[row * XSP + col];
      *(f16x8*)(aA + gi) = *(const f16x8*)&aLs[row * XSP + col];
    }
    __syncthreads();  // half=1 overwrites Raw/xsL/aLs
  }
}

// ---------------- scan pass 2: segmented carry chain ----------------
// 2a: per-segment (16 chunks) aggregate: SP = prod(P), SH = scan-h within seg.
__global__ void scan2a_kernel(const float* __restrict__ P, const float* __restrict__ H,
                              float* __restrict__ SP, float* __restrict__ SH) {
  const int u = blockIdx.x * 256 + threadIdx.x;  // 0..65535
  const int d = u & 1023;
  const int s = (u >> 10) & (NSEG - 1);
  const int b = u >> 14;
  const int gs0 = b * CPB + s * SEG;
  float p = 1.f, h = 0.f;
#pragma unroll 4
  for (int c = 0; c < SEG; ++c) {
    const size_t off = (size_t)(gs0 + c) * D_DIM + d;
    const float pp = P[off], hh = H[off];
    h = pp * h + hh;
    p *= pp;
  }
  const size_t so = (size_t)(b * NSEG + s) * D_DIM + d;
  SP[so] = p;
  SH[so] = h;
}

// 2bc: chain segment aggregates (redundantly per block; s uniform within block)
//      then expand to per-chunk carries.
__global__ void scan2bc_kernel(const float* __restrict__ P, const float* __restrict__ H,
                               const float* __restrict__ SP, const float* __restrict__ SH,
                               float* __restrict__ carry) {
  const int u = blockIdx.x * 256 + threadIdx.x;  // 0..65535
  const int d = u & 1023;
  const int s = (u >> 10) & (NSEG - 1);  // uniform within a 256-thread block
  const int b = u >> 14;
  float h = 0.f;
  for (int s2 = 0; s2 < s; ++s2) {
    const size_t off = (size_t)(b * NSEG + s2) * D_DIM + d;
    h = SP[off] * h + SH[off];
  }
  const int gs0 = b * CPB + s * SEG;
#pragma unroll 4
  for (int c = 0; c < SEG; ++c) {
    const size_t off = (size_t)(gs0 + c) * D_DIM + d;
    carry[off] = h;
    h = P[off] * h + H[off];
  }
}

// ---------------- scan pass 3: rescan with carry, write output ----------------
__global__ void scan3_kernel(const f16* __restrict__ xsA, const f16* __restrict__ aA,
                             const float* __restrict__ carry, float* __restrict__ out) {
  const int u = blockIdx.x * 256 + threadIdx.x;
  const int cg = u & 127;
  const int b = (u >> 7) & 3;
  const int ck = u >> 9;  // 0..255
  const int ch = cg * 8;
  const int base = (b * CPB + ck) * D_DIM + ch;
  float h[8];
  *(f32x4*)h = *(const f32x4*)(carry + base);
  *(f32x4*)(h + 4) = *(const f32x4*)(carry + base + 4);
  const int t0 = ck * CLEN;
#pragma unroll 2
  for (int t = t0; t < t0 + CLEN; ++t) {
    const size_t m = (size_t)b * S_LEN + t;
    f16x8 xs8 = *(const f16x8*)(xsA + m * D_DIM + ch);
    f16x8 a8 = *(const f16x8*)(aA + m * D_DIM + ch);
#pragma unroll
    for (int j = 0; j < 8; ++j) h[j] = (float)a8[j] * h[j] + (float)xs8[j];
    float* op = out + m * D_DIM + ch;
    *(f32x4*)op = *(f32x4*)h;
    *(f32x4*)(op + 4) = *(f32x4*)(h + 4);
  }
}

extern "C" void kernel_launch(void* const* d_in, const int* in_sizes, int n_in,
                              void* d_out, int out_size, void* d_ws, size_t ws_size,
                              hipStream_t stream) {
  const float* x = (const float*)d_in[0];
  const float* Wg = (const float*)d_in[1];
  const float* bg = (const float*)d_in[2];
  const float* Wv = (const float*)d_in[3];
  const float* bv = (const float*)d_in[4];
  const float* Wd = (const float*)d_in[5];
  const float* bd = (const float*)d_in[6];
  float* out = (float*)d_out;

  // workspace layout (~114 MB). SP/SH overlay the Ah region: Ah is dead once
  // gemm_fused completes, and scan2a runs strictly after it on the stream.
  char* ws = (char*)d_ws;
  f16* Ah = (f16*)(ws);                     // 33,554,432 B
  f16* Bh = (f16*)(ws + 33554432);          // 6,291,456 B (interleaved weights)
  f16* xsA = (f16*)(ws + 39845888);         // 33,554,432 B
  f16* aA = (f16*)(ws + 73400320);          // 33,554,432 B
  float* P = (float*)(ws + 106954752);      // NCHUNK*1024*4 = 4,194,304 B
  float* H = (float*)(ws + 111149056);      // 4,194,304 B
  float* carry = (float*)(ws + 115343360);  // 4,194,304 B
  float* SP = (float*)(ws);                 // 262,144 B (overlays dead Ah)
  float* SH = (float*)(ws + 262144);        // 262,144 B

  cvt_all_kernel<<<9728, 256, 0, stream>>>(x, Wg, Wv, Wd, Ah, Bh);
  gemm_fused_kernel<<<1024, 512, 0, stream>>>(Ah, Bh, bg, bv, bd, xsA, aA, P, H);
  scan2a_kernel<<<256, 256, 0, stream>>>(P, H, SP, SH);
  scan2bc_kernel<<<256, 256, 0, stream>>>(P, H, SP, SH, carry);
  scan3_kernel<<<512, 256, 0, stream>>>(xsA, aA, carry, out);
}